// Round 3
// baseline (229.719 us; speedup 1.0000x reference)
//
#include <hip/hip_runtime.h>
#include <math.h>

#define FFT_N 512
#define WAVES_PER_BLOCK 4
#define PAIRS_PER_WAVE 2
#define LDS_STRIDE 576   // per-wave region in float2; max addr used = 574

// Wave-level sync for wave-private LDS exchange: drain LDS pipe + block
// compiler motion. No __syncthreads needed (each wave owns its region).
#define WAVE_LDS_SYNC() do { \
    __builtin_amdgcn_wave_barrier(); \
    asm volatile("s_waitcnt lgkmcnt(0)" ::: "memory"); \
    __builtin_amdgcn_wave_barrier(); \
} while (0)

// In-register 8-point complex DFT (DIF radix-2^3), outputs in NATURAL order.
__device__ __forceinline__ void fft8(float* re, float* im) {
    const float C = 0.70710678118654752440f;
    float tr[8], ti[8];
    tr[0]=re[0]+re[4]; ti[0]=im[0]+im[4];
    tr[4]=re[0]-re[4]; ti[4]=im[0]-im[4];
    tr[1]=re[1]+re[5]; ti[1]=im[1]+im[5];
    tr[5]=re[1]-re[5]; ti[5]=im[1]-im[5];
    tr[2]=re[2]+re[6]; ti[2]=im[2]+im[6];
    tr[6]=re[2]-re[6]; ti[6]=im[2]-im[6];
    tr[3]=re[3]+re[7]; ti[3]=im[3]+im[7];
    tr[7]=re[3]-re[7]; ti[7]=im[3]-im[7];
    { float a=tr[5], b=ti[5]; tr[5]=C*(a+b); ti[5]=C*(b-a); }
    { float a=tr[6], b=ti[6]; tr[6]=b;       ti[6]=-a;      }
    { float a=tr[7], b=ti[7]; tr[7]=C*(b-a); ti[7]=-C*(a+b);}
    {
        float s0r=tr[0]+tr[2], s0i=ti[0]+ti[2];
        float s2r=tr[0]-tr[2], s2i=ti[0]-ti[2];
        float s1r=tr[1]+tr[3], s1i=ti[1]+ti[3];
        float dr =tr[1]-tr[3], di =ti[1]-ti[3];
        float s3r= di, s3i=-dr;
        re[0]=s0r+s1r; im[0]=s0i+s1i;
        re[2]=s2r+s3r; im[2]=s2i+s3i;
        re[4]=s0r-s1r; im[4]=s0i-s1i;
        re[6]=s2r-s3r; im[6]=s2i-s3i;
    }
    {
        float s0r=tr[4]+tr[6], s0i=ti[4]+ti[6];
        float s2r=tr[4]-tr[6], s2i=ti[4]-ti[6];
        float s1r=tr[5]+tr[7], s1i=ti[5]+ti[7];
        float dr =tr[5]-tr[7], di =ti[5]-ti[7];
        float s3r= di, s3i=-dr;
        re[1]=s0r+s1r; im[1]=s0i+s1i;
        re[3]=s2r+s3r; im[3]=s2i+s3i;
        re[5]=s0r-s1r; im[5]=s0i-s1i;
        re[7]=s2r-s3r; im[7]=s2i-s3i;
    }
}

// Apply tw[k] = base^k (chained complex multiply) to regs 1..7.
__device__ __forceinline__ void twiddle_chain(float* re, float* im,
                                              float c, float s) {
    float cr = c, ci = s;
#pragma unroll
    for (int k = 1; k < 8; ++k) {
        float a = re[k], b = im[k];
        re[k] = a * cr - b * ci;
        im[k] = a * ci + b * cr;
        float ncr = cr * c - ci * s;
        float nci = cr * s + ci * c;
        cr = ncr; ci = nci;
    }
}

// Exchange-3 slot swizzle: A3(k) = 64*(k>>6) + swz3(k&63).
// swz3 bank-pair bits: [m0^m2, m3, m4, m5]; high bits [m1, m2].
// Injective in m-bits{0,3,4,5} (write via rot3(lane)) and in
// m-bits{2,3,4,5} (both mirrored reads) within every 16-lane phase.
__device__ __forceinline__ int swz3(int m) {
    return ((m ^ (m >> 2)) & 1)
         | (((m >> 3) & 7) << 1)
         | (((m >> 1) & 1) << 4)
         | (((m >> 2) & 1) << 5);
}

// One wave per PAIR of rows: z = x[2q] + i*x[2q+1], one 512-pt complex FFT,
// unpack Re(A)= (ReZ[k]+ReZ[N-k])/2, Re(B) = (ImZ[k]+ImZ[N-k])/2.
// Decimation: n = 64*n1 + 8*n2 + n3 ; k = k1 + 8*k2 + 64*k3.
// Each wave processes PAIRS_PER_WAVE pairs, prefetching the next pair's
// global data under the current pair's compute.
// All LDS exchanges verified conflict-free under the 16-lane b64 phase model.
__global__ __launch_bounds__(256) void fft512_pack2_kernel(
        const float* __restrict__ x,
        const float* __restrict__ win,
        float* __restrict__ out) {
    __shared__ float2 lds[WAVES_PER_BLOCK * LDS_STRIDE];

    const int wave = threadIdx.x >> 6;
    const int lane = threadIdx.x & 63;
    float2* __restrict__ L = lds + wave * LDS_STRIDE;

    const int t4   = lane << 2;
    const int u    = lane & 15;
    const int pp   = lane >> 4;
    const int x0sw = (lane >> 2) & 3;            // exch-0 write XOR (on j)
    const int l0r  = lane ^ pp;                  // exch-0 read lane index
    const int k1p  = lane >> 3;                  // exch-1 read / exch-2 write role
    const int n3p  = lane & 7;
    const int rl   = (lane >> 3) | ((lane & 7) << 3);  // post-C k&63
    const int s3w  = swz3(rl);                   // exch-3 write slot

    int sm[4], smm[4];
#pragma unroll
    for (int j = 0; j < 4; ++j) {
        const int m = 4 * u + j;
        sm[j]  = swz3(m);
        smm[j] = swz3((64 - m) & 63);
    }

    // Twiddle bases (lane-only) — shared by both pairs.
    float cA, sA, cB, sB;
    __sincosf(-6.283185307179586f * (float)lane * (1.0f / 512.0f), &sA, &cA);
    __sincosf(-6.283185307179586f * (float)n3p  * (1.0f / 64.0f),  &sB, &cB);

    const int pair0 = (blockIdx.x * WAVES_PER_BLOCK + wave) * PAIRS_PER_WAVE;

    const float4 w0 = *(const float4*)(win + t4);
    const float4 w1 = *(const float4*)(win + t4 + 256);

    const float* __restrict__ xp0 = x + (size_t)(2 * pair0) * FFT_N;
    float4 ca0 = *(const float4*)(xp0 + t4);
    float4 cb0 = *(const float4*)(xp0 + FFT_N + t4);
    float4 ca1 = *(const float4*)(xp0 + t4 + 256);
    float4 cb1 = *(const float4*)(xp0 + FFT_N + t4 + 256);

#pragma unroll
    for (int p = 0; p < PAIRS_PER_WAVE; ++p) {
        // ---- Exchange 0 write: A0(i) = i ^ ((i>>4)&3) = base + (j^x0sw) ----
        {
            const float* a0 = (const float*)&ca0;
            const float* b0 = (const float*)&cb0;
            const float* a1 = (const float*)&ca1;
            const float* b1 = (const float*)&cb1;
            const float* W0 = (const float*)&w0;
            const float* W1 = (const float*)&w1;
#pragma unroll
            for (int j = 0; j < 4; ++j) {
                L[t4 +       (j ^ x0sw)] = make_float2(a0[j] * W0[j], b0[j] * W0[j]);
                L[t4 + 256 + (j ^ x0sw)] = make_float2(a1[j] * W1[j], b1[j] * W1[j]);
            }
        }
        WAVE_LDS_SYNC();

        // ---- Prefetch next pair (issues now; completes under this compute) ----
        float4 na0, nb0, na1, nb1;
        if (p + 1 < PAIRS_PER_WAVE) {
            const float* __restrict__ np = x + (size_t)(2 * (pair0 + p + 1)) * FFT_N;
            na0 = *(const float4*)(np + t4);
            nb0 = *(const float4*)(np + FFT_N + t4);
            na1 = *(const float4*)(np + t4 + 256);
            nb1 = *(const float4*)(np + FFT_N + t4 + 256);
        } else {
            na0 = ca0; nb0 = cb0; na1 = ca1; nb1 = cb1;
        }

        // ---- Exchange 0 read: element 64*n1 + lane is at 64*n1 + (lane^pp) ----
        float re[8], im[8];
#pragma unroll
        for (int n1 = 0; n1 < 8; ++n1) {
            float2 v = L[n1 * 64 + l0r];
            re[n1] = v.x; im[n1] = v.y;
        }
        WAVE_LDS_SYNC();

        // ---- Stage A: DFT8 over n1 + twiddle W512^{lane*k1} ----
        fft8(re, im);
        twiddle_chain(re, im, cA, sA);

        // ---- Exchange 1: addr = k1*72 + (8*n2 + n3) ----
#pragma unroll
        for (int k1 = 0; k1 < 8; ++k1)
            L[k1 * 72 + lane] = make_float2(re[k1], im[k1]);
        WAVE_LDS_SYNC();
#pragma unroll
        for (int n2 = 0; n2 < 8; ++n2) {
            float2 v = L[k1p * 72 + n2 * 8 + n3p];
            re[n2] = v.x; im[n2] = v.y;
        }
        WAVE_LDS_SYNC();

        // ---- Stage B: DFT8 over n2 + twiddle W64^{n3p*k2} ----
        fft8(re, im);
        twiddle_chain(re, im, cB, sB);

        // ---- Exchange 2: addr = (k1*8 + k2)*9 + n3 ----
#pragma unroll
        for (int k2 = 0; k2 < 8; ++k2)
            L[(k1p * 8 + k2) * 9 + n3p] = make_float2(re[k2], im[k2]);
        WAVE_LDS_SYNC();
        // Read role: k1 = lane>>3, k2 = lane&7  =>  addr = lane*9 + n3.
#pragma unroll
        for (int n3 = 0; n3 < 8; ++n3) {
            float2 v = L[lane * 9 + n3];
            re[n3] = v.x; im[n3] = v.y;
        }
        WAVE_LDS_SYNC();

        // ---- Stage C ----
        fft8(re, im);
        // Thread holds Z[k], k = rl + 64*k3.

        // ---- Exchange 3: Z[k] at 64*(k>>6) + swz3(k&63) ----
#pragma unroll
        for (int k3 = 0; k3 < 8; ++k3)
            L[(k3 << 6) + s3w] = make_float2(re[k3], im[k3]);
        WAVE_LDS_SYNC();

        float* __restrict__ o0 = out + (size_t)(2 * (pair0 + p)) * FFT_N;
        float* __restrict__ o1 = o0 + FFT_N;
#pragma unroll
        for (int half = 0; half < 2; ++half) {
            const int hk = 4 * half + pp;
            float4 ra, rb;
            float* pa = (float*)&ra;
            float* pb = (float*)&rb;
#pragma unroll
            for (int j = 0; j < 4; ++j) {
                const int m  = 4 * u + j;
                const int hn = ((512 - (hk << 6) - m) >> 6) & 7;
                const float2 zk = L[(hk << 6) + sm[j]];
                const float2 zn = L[(hn << 6) + smm[j]];
                pa[j] = 0.5f * (zk.x + zn.x);
                pb[j] = 0.5f * (zk.y + zn.y);
            }
            *(float4*)(o0 + 256 * half + t4) = ra;
            *(float4*)(o1 + 256 * half + t4) = rb;
        }
        WAVE_LDS_SYNC();   // WAR: store-reads done before next pair's exch-0 writes

        ca0 = na0; cb0 = nb0; ca1 = na1; cb1 = nb1;
    }
}

extern "C" void kernel_launch(void* const* d_in, const int* in_sizes, int n_in,
                              void* d_out, int out_size, void* d_ws, size_t ws_size,
                              hipStream_t stream) {
    const float* x   = (const float*)d_in[0];
    const float* win = (const float*)d_in[1];
    float* out       = (float*)d_out;

    const int rows   = in_sizes[0] / FFT_N;                      // 65536
    const int pairs  = rows / 2;                                 // 32768
    const int blocks = pairs / (WAVES_PER_BLOCK * PAIRS_PER_WAVE); // 4096
    hipLaunchKernelGGL(fft512_pack2_kernel, dim3(blocks), dim3(256), 0, stream,
                       x, win, out);
}

// Round 4
// 228.619 us; speedup vs baseline: 1.0048x; 1.0048x over previous
//
#include <hip/hip_runtime.h>
#include <math.h>

#define FFT_N 512
#define WAVES_PER_BLOCK 4
#define PAIRS_PER_WAVE 2
#define LDS_STRIDE 576   // per-wave region in float2; max addr used = 574

// Compile-time-only fence: orders the C++ LDS accesses (memory clobber) and
// pins machine-scheduler motion (wave_barrier) — emits ZERO instructions.
// Correctness: each wave owns its LDS region, and same-wave DS operations
// are processed IN ORDER by hardware, so write->read needs no s_waitcnt;
// the compiler inserts counted lgkmcnt(N) before register USES only.
// This keeps the LDS pipe full instead of draining it 8x per FFT.
#define WAVE_LDS_FENCE() do { \
    asm volatile("" ::: "memory"); \
    __builtin_amdgcn_wave_barrier(); \
    asm volatile("" ::: "memory"); \
} while (0)

// In-register 8-point complex DFT (DIF radix-2^3), outputs in NATURAL order.
__device__ __forceinline__ void fft8(float* re, float* im) {
    const float C = 0.70710678118654752440f;
    float tr[8], ti[8];
    tr[0]=re[0]+re[4]; ti[0]=im[0]+im[4];
    tr[4]=re[0]-re[4]; ti[4]=im[0]-im[4];
    tr[1]=re[1]+re[5]; ti[1]=im[1]+im[5];
    tr[5]=re[1]-re[5]; ti[5]=im[1]-im[5];
    tr[2]=re[2]+re[6]; ti[2]=im[2]+im[6];
    tr[6]=re[2]-re[6]; ti[6]=im[2]-im[6];
    tr[3]=re[3]+re[7]; ti[3]=im[3]+im[7];
    tr[7]=re[3]-re[7]; ti[7]=im[3]-im[7];
    { float a=tr[5], b=ti[5]; tr[5]=C*(a+b); ti[5]=C*(b-a); }
    { float a=tr[6], b=ti[6]; tr[6]=b;       ti[6]=-a;      }
    { float a=tr[7], b=ti[7]; tr[7]=C*(b-a); ti[7]=-C*(a+b);}
    {
        float s0r=tr[0]+tr[2], s0i=ti[0]+ti[2];
        float s2r=tr[0]-tr[2], s2i=ti[0]-ti[2];
        float s1r=tr[1]+tr[3], s1i=ti[1]+ti[3];
        float dr =tr[1]-tr[3], di =ti[1]-ti[3];
        float s3r= di, s3i=-dr;
        re[0]=s0r+s1r; im[0]=s0i+s1i;
        re[2]=s2r+s3r; im[2]=s2i+s3i;
        re[4]=s0r-s1r; im[4]=s0i-s1i;
        re[6]=s2r-s3r; im[6]=s2i-s3i;
    }
    {
        float s0r=tr[4]+tr[6], s0i=ti[4]+ti[6];
        float s2r=tr[4]-tr[6], s2i=ti[4]-ti[6];
        float s1r=tr[5]+tr[7], s1i=ti[5]+ti[7];
        float dr =tr[5]-tr[7], di =ti[5]-ti[7];
        float s3r= di, s3i=-dr;
        re[1]=s0r+s1r; im[1]=s0i+s1i;
        re[3]=s2r+s3r; im[3]=s2i+s3i;
        re[5]=s0r-s1r; im[5]=s0i-s1i;
        re[7]=s2r-s3r; im[7]=s2i-s3i;
    }
}

// Apply tw[k] = base^k (chained complex multiply) to regs 1..7.
__device__ __forceinline__ void twiddle_chain(float* re, float* im,
                                              float c, float s) {
    float cr = c, ci = s;
#pragma unroll
    for (int k = 1; k < 8; ++k) {
        float a = re[k], b = im[k];
        re[k] = a * cr - b * ci;
        im[k] = a * ci + b * cr;
        float ncr = cr * c - ci * s;
        float nci = cr * s + ci * c;
        cr = ncr; ci = nci;
    }
}

// Exchange-3 slot swizzle: A3(k) = 64*(k>>6) + swz3(k&63).
// swz3 bank-pair bits: [m0^m2, m3, m4, m5]; high bits [m1, m2].
// Injective in m-bits{0,3,4,5} (write via rot3(lane)) and in
// m-bits{2,3,4,5} (both mirrored reads) within every 16-lane phase.
__device__ __forceinline__ int swz3(int m) {
    return ((m ^ (m >> 2)) & 1)
         | (((m >> 3) & 7) << 1)
         | (((m >> 1) & 1) << 4)
         | (((m >> 2) & 1) << 5);
}

// One wave per PAIR of rows: z = x[2q] + i*x[2q+1], one 512-pt complex FFT,
// unpack Re(A)= (ReZ[k]+ReZ[N-k])/2, Re(B) = (ImZ[k]+ImZ[N-k])/2.
// Decimation: n = 64*n1 + 8*n2 + n3 ; k = k1 + 8*k2 + 64*k3.
// Each wave processes PAIRS_PER_WAVE pairs, prefetching the next pair's
// global data under the current pair's compute.
// All LDS exchanges conflict-free under the 16-lane b64 phase model.
__global__ __launch_bounds__(256) void fft512_pack2_kernel(
        const float* __restrict__ x,
        const float* __restrict__ win,
        float* __restrict__ out) {
    __shared__ float2 lds[WAVES_PER_BLOCK * LDS_STRIDE];

    const int wave = threadIdx.x >> 6;
    const int lane = threadIdx.x & 63;
    float2* __restrict__ L = lds + wave * LDS_STRIDE;

    const int t4   = lane << 2;
    const int u    = lane & 15;
    const int pp   = lane >> 4;
    const int x0sw = (lane >> 2) & 3;            // exch-0 write XOR (on j)
    const int l0r  = lane ^ pp;                  // exch-0 read lane index
    const int k1p  = lane >> 3;                  // exch-1 read / exch-2 write role
    const int n3p  = lane & 7;
    const int rl   = (lane >> 3) | ((lane & 7) << 3);  // post-C k&63
    const int s3w  = swz3(rl);                   // exch-3 write slot

    int sm[4], smm[4];
#pragma unroll
    for (int j = 0; j < 4; ++j) {
        const int m = 4 * u + j;
        sm[j]  = swz3(m);
        smm[j] = swz3((64 - m) & 63);
    }

    // Twiddle bases (lane-only) — shared by both pairs.
    float cA, sA, cB, sB;
    __sincosf(-6.283185307179586f * (float)lane * (1.0f / 512.0f), &sA, &cA);
    __sincosf(-6.283185307179586f * (float)n3p  * (1.0f / 64.0f),  &sB, &cB);

    const int pair0 = (blockIdx.x * WAVES_PER_BLOCK + wave) * PAIRS_PER_WAVE;

    const float4 w0 = *(const float4*)(win + t4);
    const float4 w1 = *(const float4*)(win + t4 + 256);

    const float* __restrict__ xp0 = x + (size_t)(2 * pair0) * FFT_N;
    float4 ca0 = *(const float4*)(xp0 + t4);
    float4 cb0 = *(const float4*)(xp0 + FFT_N + t4);
    float4 ca1 = *(const float4*)(xp0 + t4 + 256);
    float4 cb1 = *(const float4*)(xp0 + FFT_N + t4 + 256);

#pragma unroll
    for (int p = 0; p < PAIRS_PER_WAVE; ++p) {
        // ---- Exchange 0 write: A0(i) = i ^ ((i>>4)&3) = base + (j^x0sw) ----
        {
            const float* a0 = (const float*)&ca0;
            const float* b0 = (const float*)&cb0;
            const float* a1 = (const float*)&ca1;
            const float* b1 = (const float*)&cb1;
            const float* W0 = (const float*)&w0;
            const float* W1 = (const float*)&w1;
#pragma unroll
            for (int j = 0; j < 4; ++j) {
                L[t4 +       (j ^ x0sw)] = make_float2(a0[j] * W0[j], b0[j] * W0[j]);
                L[t4 + 256 + (j ^ x0sw)] = make_float2(a1[j] * W1[j], b1[j] * W1[j]);
            }
        }
        WAVE_LDS_FENCE();

        // ---- Prefetch next pair (issues now; completes under this compute) ----
        float4 na0, nb0, na1, nb1;
        if (p + 1 < PAIRS_PER_WAVE) {
            const float* __restrict__ np = x + (size_t)(2 * (pair0 + p + 1)) * FFT_N;
            na0 = *(const float4*)(np + t4);
            nb0 = *(const float4*)(np + FFT_N + t4);
            na1 = *(const float4*)(np + t4 + 256);
            nb1 = *(const float4*)(np + FFT_N + t4 + 256);
        } else {
            na0 = ca0; nb0 = cb0; na1 = ca1; nb1 = cb1;
        }

        // ---- Exchange 0 read: element 64*n1 + lane is at 64*n1 + (lane^pp) ----
        float re[8], im[8];
#pragma unroll
        for (int n1 = 0; n1 < 8; ++n1) {
            float2 v = L[n1 * 64 + l0r];
            re[n1] = v.x; im[n1] = v.y;
        }
        WAVE_LDS_FENCE();

        // ---- Stage A: DFT8 over n1 + twiddle W512^{lane*k1} ----
        fft8(re, im);
        twiddle_chain(re, im, cA, sA);

        // ---- Exchange 1: addr = k1*72 + (8*n2 + n3) ----
#pragma unroll
        for (int k1 = 0; k1 < 8; ++k1)
            L[k1 * 72 + lane] = make_float2(re[k1], im[k1]);
        WAVE_LDS_FENCE();
#pragma unroll
        for (int n2 = 0; n2 < 8; ++n2) {
            float2 v = L[k1p * 72 + n2 * 8 + n3p];
            re[n2] = v.x; im[n2] = v.y;
        }
        WAVE_LDS_FENCE();

        // ---- Stage B: DFT8 over n2 + twiddle W64^{n3p*k2} ----
        fft8(re, im);
        twiddle_chain(re, im, cB, sB);

        // ---- Exchange 2: addr = (k1*8 + k2)*9 + n3 ----
#pragma unroll
        for (int k2 = 0; k2 < 8; ++k2)
            L[(k1p * 8 + k2) * 9 + n3p] = make_float2(re[k2], im[k2]);
        WAVE_LDS_FENCE();
        // Read role: k1 = lane>>3, k2 = lane&7  =>  addr = lane*9 + n3.
#pragma unroll
        for (int n3 = 0; n3 < 8; ++n3) {
            float2 v = L[lane * 9 + n3];
            re[n3] = v.x; im[n3] = v.y;
        }
        WAVE_LDS_FENCE();

        // ---- Stage C ----
        fft8(re, im);
        // Thread holds Z[k], k = rl + 64*k3.

        // ---- Exchange 3: Z[k] at 64*(k>>6) + swz3(k&63) ----
#pragma unroll
        for (int k3 = 0; k3 < 8; ++k3)
            L[(k3 << 6) + s3w] = make_float2(re[k3], im[k3]);
        WAVE_LDS_FENCE();

        float* __restrict__ o0 = out + (size_t)(2 * (pair0 + p)) * FFT_N;
        float* __restrict__ o1 = o0 + FFT_N;
#pragma unroll
        for (int half = 0; half < 2; ++half) {
            const int hk = 4 * half + pp;
            float4 ra, rb;
            float* pa = (float*)&ra;
            float* pb = (float*)&rb;
#pragma unroll
            for (int j = 0; j < 4; ++j) {
                const int m  = 4 * u + j;
                const int hn = ((512 - (hk << 6) - m) >> 6) & 7;
                const float2 zk = L[(hk << 6) + sm[j]];
                const float2 zn = L[(hn << 6) + smm[j]];
                pa[j] = 0.5f * (zk.x + zn.x);
                pb[j] = 0.5f * (zk.y + zn.y);
            }
            *(float4*)(o0 + 256 * half + t4) = ra;
            *(float4*)(o1 + 256 * half + t4) = rb;
        }
        WAVE_LDS_FENCE();   // order: output reads precede next pair's exch-0 writes

        ca0 = na0; cb0 = nb0; ca1 = na1; cb1 = nb1;
    }
}

extern "C" void kernel_launch(void* const* d_in, const int* in_sizes, int n_in,
                              void* d_out, int out_size, void* d_ws, size_t ws_size,
                              hipStream_t stream) {
    const float* x   = (const float*)d_in[0];
    const float* win = (const float*)d_in[1];
    float* out       = (float*)d_out;

    const int rows   = in_sizes[0] / FFT_N;                      // 65536
    const int pairs  = rows / 2;                                 // 32768
    const int blocks = pairs / (WAVES_PER_BLOCK * PAIRS_PER_WAVE); // 4096
    hipLaunchKernelGGL(fft512_pack2_kernel, dim3(blocks), dim3(256), 0, stream,
                       x, win, out);
}